// Round 1
// baseline (330.315 us; speedup 1.0000x reference)
//
#include <hip/hip_runtime.h>

// VQ-VAE VectorQuantizer forward, MI355X (gfx950)
// inputs:  d_in[0] = inputs  [64,32,32,64] f32  (N=65536 rows, D=64)
//          d_in[1] = context [1] (unused)
//          d_in[2] = embeddings [64,512] f32    (D=64, K=512)
// out (flat f32, concatenated):
//   quantized [4194304] | loss [1] | perplexity [1] | encodings [33554432]
//   | encoding_indices [65536] (as float) | distances [33554432]

#define NROWS 65536
#define DIM 64
#define KCODES 512
#define ROWS_PER_BLOCK 64

#define QUANT_OFF 0ull
#define LOSS_OFF  4194304ull
#define PERP_OFF  4194305ull
#define ENC_OFF   4194306ull
#define IDX_OFF   37748738ull
#define DIST_OFF  37814274ull

__global__ __launch_bounds__(512) void vq_main(
    const float* __restrict__ inp, const float* __restrict__ emb,
    float* __restrict__ out, int* __restrict__ hist,
    float* __restrict__ loss_ws)
{
    __shared__ float s_sumx2[ROWS_PER_BLOCK];
    __shared__ float s_bd[2][8];
    __shared__ int   s_bk[2][8];

    const int tid  = threadIdx.x;
    const int w    = tid >> 6;      // wave 0..7
    const int lane = tid & 63;
    const int k    = (w << 6) | lane;   // this thread's codebook column
    const int rbase = blockIdx.x * ROWS_PER_BLOCK;

    // ---- load this lane's codebook column into VGPRs (coalesced per d) ----
    float e[DIM];
#pragma unroll
    for (int d = 0; d < DIM; ++d) e[d] = emb[(size_t)d * KCODES + k];

    float se0 = 0.f, se1 = 0.f, se2 = 0.f, se3 = 0.f;
#pragma unroll
    for (int d = 0; d < DIM; d += 4) {
        se0 = fmaf(e[d + 0], e[d + 0], se0);
        se1 = fmaf(e[d + 1], e[d + 1], se1);
        se2 = fmaf(e[d + 2], e[d + 2], se2);
        se3 = fmaf(e[d + 3], e[d + 3], se3);
    }
    const float sume2 = (se0 + se1) + (se2 + se3);

    // ---- per-row ||x||^2 for this block's 64 rows (wave 0, line-dense) ----
    if (w == 0) {
        const float4* xr = (const float4*)(inp + (size_t)(rbase + lane) * DIM);
        float s0 = 0.f, s1 = 0.f, s2 = 0.f, s3 = 0.f;
#pragma unroll
        for (int j = 0; j < 16; ++j) {
            float4 v = xr[j];
            s0 = fmaf(v.x, v.x, s0); s1 = fmaf(v.y, v.y, s1);
            s2 = fmaf(v.z, v.z, s2); s3 = fmaf(v.w, v.w, s3);
        }
        s_sumx2[lane] = (s0 + s1) + (s2 + s3);
    }
    __syncthreads();

    float* dist_out = out + DIST_OFF;
    float* enc_out  = out + ENC_OFF;
    float* q_out    = out + QUANT_OFF;
    float* idx_out  = out + IDX_OFF;

    float loss_acc = 0.f;

    for (int r0 = 0; r0 < ROWS_PER_BLOCK; ++r0) {
        const int r = rbase + r0;
        const int par = r0 & 1;

        // x is wave-uniform -> scalar loads; e in VGPRs -> v_fmac v,s,v
        const float4* xp4 = (const float4*)(inp + (size_t)r * DIM);
        float a0 = 0.f, a1 = 0.f, a2 = 0.f, a3 = 0.f;
#pragma unroll
        for (int j = 0; j < 16; ++j) {
            float4 xv = xp4[j];
            a0 = fmaf(xv.x, e[4 * j + 0], a0);
            a1 = fmaf(xv.y, e[4 * j + 1], a1);
            a2 = fmaf(xv.z, e[4 * j + 2], a2);
            a3 = fmaf(xv.w, e[4 * j + 3], a3);
        }
        const float dot = (a0 + a1) + (a2 + a3);
        const float dist = fmaf(-2.f, dot, s_sumx2[r0]) + sume2;

        // coalesced: consecutive lanes -> consecutive k
        dist_out[(size_t)r * KCODES + k] = dist;

        // wave-level argmin (tie -> smaller k, matches first-argmax)
        float bd = dist; int bk = k;
#pragma unroll
        for (int off = 32; off; off >>= 1) {
            float od = __shfl_xor(bd, off);
            int   ok = __shfl_xor(bk, off);
            if (od < bd || (od == bd && ok < bk)) { bd = od; bk = ok; }
        }
        if (lane == 0) { s_bd[par][w] = bd; s_bk[par][w] = bk; }
        __syncthreads();

        // block-level combine (all threads, broadcast reads, ascending order)
        float fd = s_bd[par][0]; int fi = s_bk[par][0];
#pragma unroll
        for (int w2 = 1; w2 < 8; ++w2) {
            float od = s_bd[par][w2]; int ok = s_bk[par][w2];
            if (od < fd || (od == fd && ok < fi)) { fd = od; fi = ok; }
        }

        // one-hot encodings, coalesced
        enc_out[(size_t)r * KCODES + k] = (k == fi) ? 1.f : 0.f;

        // rotate the "extra duties" wave to balance load
        if (w == (r0 & 7)) {
            // quantized row = embeddings column fi (gather, L2-resident)
            float q = emb[(size_t)lane * KCODES + fi];
            q_out[(size_t)r * DIM + lane] = q;
            if (lane == 0) {
                idx_out[r] = (float)fi;
                atomicAdd(&hist[fi], 1);
                loss_acc += fd;   // sum_d (q-x)^2 == min distance
            }
        }
    }
    if (lane == 0) atomicAdd(loss_ws, loss_acc);
}

__global__ __launch_bounds__(512) void vq_final(
    const int* __restrict__ hist, const float* __restrict__ loss_ws,
    float* __restrict__ out)
{
    __shared__ float s_red[8];
    const int tid = threadIdx.x;
    const int w = tid >> 6, lane = tid & 63;

    float p = (float)hist[tid] * (1.f / 65536.f);
    float t = p * logf(p + 1e-10f);   // p==0 -> 0 * finite = 0
#pragma unroll
    for (int off = 32; off; off >>= 1) t += __shfl_xor(t, off);
    if (lane == 0) s_red[w] = t;
    __syncthreads();
    if (tid == 0) {
        float s = 0.f;
#pragma unroll
        for (int i = 0; i < 8; ++i) s += s_red[i];
        out[PERP_OFF] = expf(-s);
        // loss = (1 + 0.25) * mean((q - x)^2) over 64*32*32*64 elements
        out[LOSS_OFF] = loss_ws[0] * (1.25f / 4194304.f);
    }
}

extern "C" void kernel_launch(void* const* d_in, const int* in_sizes, int n_in,
                              void* d_out, int out_size, void* d_ws, size_t ws_size,
                              hipStream_t stream) {
    const float* inp = (const float*)d_in[0];
    const float* emb = (const float*)d_in[2];
    float* out = (float*)d_out;
    int*   hist    = (int*)d_ws;                       // 512 ints
    float* loss_ws = (float*)((char*)d_ws + 2048);     // 1 float

    hipMemsetAsync(d_ws, 0, 2052, stream);
    vq_main<<<dim3(NROWS / ROWS_PER_BLOCK), dim3(512), 0, stream>>>(
        inp, emb, out, hist, loss_ws);
    vq_final<<<dim3(1), dim3(512), 0, stream>>>(hist, loss_ws, out);
}